// Round 1
// baseline (1204.573 us; speedup 1.0000x reference)
//
#include <hip/hip_runtime.h>
#include <math.h>

#define HIDDEN 2560
#define HEAD_DIM 128
#define NH 32
#define NKV 8
#define TNEW 16
#define TCACHE 4080
#define TTOT 4096
#define INTER 9728
#define QDIM 4096
#define KVDIM 1024

static __device__ __forceinline__ float4 ld4(const float* p){ return *(const float4*)p; }

// ---------------- RMSNorm over x (16 x 2560) ----------------
__global__ void rms_kernel(const float* __restrict__ x, const float* __restrict__ w,
                           float* __restrict__ y) {
  int t = blockIdx.x;
  int tid = threadIdx.x;
  const float* xp = x + (size_t)t * HIDDEN;
  float v[10];
  float ss = 0.f;
#pragma unroll
  for (int i = 0; i < 10; i++) { v[i] = xp[i * 256 + tid]; ss += v[i] * v[i]; }
#pragma unroll
  for (int off = 32; off > 0; off >>= 1) ss += __shfl_down(ss, off, 64);
  __shared__ float sred[4];
  if ((tid & 63) == 0) sred[tid >> 6] = ss;
  __syncthreads();
  ss = sred[0] + sred[1] + sred[2] + sred[3];
  float r = rsqrtf(ss / (float)HIDDEN + 1e-6f);
  float* yp = y + (size_t)t * HIDDEN;
#pragma unroll
  for (int i = 0; i < 10; i++) yp[i * 256 + tid] = v[i] * r * w[i * 256 + tid];
}

// ---------------- QKV projection, split-K x2 ----------------
// grid = 2*768 blocks of 128 threads; 8 rows x 16 tokens per block
__global__ void qkv_kernel(const float* __restrict__ y, const float* __restrict__ qw,
                           const float* __restrict__ kw, const float* __restrict__ vw,
                           float* __restrict__ q_ws, float* __restrict__ k_ws,
                           float* __restrict__ v_ws) {
  int t = threadIdx.x & 15;
  int osub = threadIdx.x >> 4;
  int chunk = blockIdx.x / 768;
  int brow = blockIdx.x % 768;
  int row = brow * 8 + osub;  // 0..6143
  const float* W; float* out; int o; int ostride; int coff;
  if (row < 4096)      { W = qw + (size_t)row * HIDDEN;          out = q_ws; o = row;        ostride = QDIM;  coff = 65536; }
  else if (row < 5120) { W = kw + (size_t)(row - 4096) * HIDDEN; out = k_ws; o = row - 4096; ostride = KVDIM; coff = 16384; }
  else                 { W = vw + (size_t)(row - 5120) * HIDDEN; out = v_ws; o = row - 5120; ostride = KVDIM; coff = 16384; }
  int k0 = chunk * 1280;
  const float* a = y + (size_t)t * HIDDEN + k0;
  const float* wp = W + k0;
  float acc = 0.f;
#pragma unroll 4
  for (int k = 0; k < 1280; k += 4) {
    float4 w4 = ld4(wp + k);
    float4 a4 = ld4(a + k);
    acc += w4.x * a4.x + w4.y * a4.y + w4.z * a4.z + w4.w * a4.w;
  }
  out[(size_t)chunk * coff + (size_t)t * ostride + o] = acc;
}

// ---------------- q/k rmsnorm + rope, v copy ----------------
// grid 648 blocks of 128: 0..511 q rows (h,t), 512..639 k rows (g,t), 640..647 v copy
__global__ void normrope_kernel(const float* __restrict__ q_ws, const float* __restrict__ k_ws,
                                const float* __restrict__ v_ws,
                                const float* __restrict__ qnw, const float* __restrict__ knw,
                                const float* __restrict__ cosq, const float* __restrict__ sinq,
                                const float* __restrict__ cosk, const float* __restrict__ sink,
                                float* __restrict__ q_r, float* __restrict__ out_k,
                                float* __restrict__ out_v) {
  int b = blockIdx.x;
  int d = threadIdx.x;
  __shared__ float sn[128];
  __shared__ float sred[2];
  if (b < 640) {
    float val; const float* nw; int t;
    if (b < 512) {
      int h = b >> 4; t = b & 15;
      size_t idx = (size_t)t * QDIM + h * HEAD_DIM + d;
      val = q_ws[idx] + q_ws[65536 + idx];
      nw = qnw;
    } else {
      int g = (b - 512) >> 4; t = (b - 512) & 15;
      size_t idx = (size_t)t * KVDIM + g * HEAD_DIM + d;
      val = k_ws[idx] + k_ws[16384 + idx];
      nw = knw;
    }
    float ss = val * val;
#pragma unroll
    for (int off = 32; off > 0; off >>= 1) ss += __shfl_down(ss, off, 64);
    if ((d & 63) == 0) sred[d >> 6] = ss;
    __syncthreads();
    ss = sred[0] + sred[1];
    float r = rsqrtf(ss / 128.f + 1e-6f);
    float n = val * r * nw[d];
    sn[d] = n;
    __syncthreads();
    float rot = (d < 64) ? -sn[d + 64] : sn[d - 64];
    const float* C = (b < 512) ? cosq : cosk;
    const float* S = (b < 512) ? sinq : sink;
    float res = n * C[t * 128 + d] + rot * S[t * 128 + d];
    if (b < 512) {
      int h = b >> 4;
      q_r[((size_t)(h * 16 + t)) * 128 + d] = res;
    } else {
      int g = (b - 512) >> 4;
      out_k[((size_t)(g * 16 + t)) * 128 + d] = res;
    }
  } else {
    int bb = b - 640;
#pragma unroll
    for (int i = 0; i < 16; i++) {
      int idx = bb * 2048 + i * 128 + d;  // [g][t][d]
      int g = idx >> 11; int t2 = (idx >> 7) & 15; int dd = idx & 127;
      size_t sidx = (size_t)t2 * KVDIM + g * HEAD_DIM + dd;
      out_v[idx] = v_ws[sidx] + v_ws[16384 + sidx];
    }
  }
}

// ---------------- scores = q @ K^T * scale + mask ----------------
// grid = 8 g * 64 jblk, 256 threads (wave = 64 qrows at one j)
__global__ __launch_bounds__(256) void scores_kernel(const float* __restrict__ q_r,
                                                     const float* __restrict__ ck,
                                                     const float* __restrict__ nk,
                                                     const float* __restrict__ mask,
                                                     float* __restrict__ sc) {
  int g = blockIdx.x >> 6;
  int jblk = blockIdx.x & 63;
  int lane = threadIdx.x & 63;  // qrow = hsub*16 + t
  int wv = threadIdx.x >> 6;
  const float* qp = q_r + ((size_t)g * 64 + lane) * 128;
  float4 qreg[32];
#pragma unroll
  for (int i = 0; i < 32; i++) qreg[i] = ld4(qp + i * 4);
  int t = lane & 15;
  const float scale = 0.08838834764831845f;
  for (int jj = 0; jj < 16; jj++) {
    int j = jblk * 64 + jj * 4 + wv;
    const float* kp = (j < TCACHE) ? ck + ((size_t)g * TCACHE + j) * 128
                                   : nk + ((size_t)g * 16 + (j - TCACHE)) * 128;
    float acc = 0.f;
#pragma unroll
    for (int i = 0; i < 32; i++) {
      float4 k4 = ld4(kp + i * 4);
      acc += qreg[i].x * k4.x + qreg[i].y * k4.y + qreg[i].z * k4.z + qreg[i].w * k4.w;
    }
    sc[((size_t)g * 64 + lane) * TTOT + j] = acc * scale + mask[t * TTOT + j];
  }
}

// ---------------- softmax over 4096, one block per (h,t) row ----------------
__global__ void softmax_kernel(float* __restrict__ sc) {
  int row = blockIdx.x;
  int tid = threadIdx.x;
  float* p = sc + (size_t)row * TTOT;
  float4 v[4];
  float mx = -1e30f;
#pragma unroll
  for (int i = 0; i < 4; i++) {
    v[i] = ld4(p + (i * 256 + tid) * 4);
    mx = fmaxf(mx, fmaxf(fmaxf(v[i].x, v[i].y), fmaxf(v[i].z, v[i].w)));
  }
#pragma unroll
  for (int off = 32; off > 0; off >>= 1) mx = fmaxf(mx, __shfl_down(mx, off, 64));
  __shared__ float rmax[4], rsum[4];
  if ((tid & 63) == 0) rmax[tid >> 6] = mx;
  __syncthreads();
  mx = fmaxf(fmaxf(rmax[0], rmax[1]), fmaxf(rmax[2], rmax[3]));
  float sum = 0.f;
#pragma unroll
  for (int i = 0; i < 4; i++) {
    v[i].x = __expf(v[i].x - mx); v[i].y = __expf(v[i].y - mx);
    v[i].z = __expf(v[i].z - mx); v[i].w = __expf(v[i].w - mx);
    sum += v[i].x + v[i].y + v[i].z + v[i].w;
  }
#pragma unroll
  for (int off = 32; off > 0; off >>= 1) sum += __shfl_down(sum, off, 64);
  if ((tid & 63) == 0) rsum[tid >> 6] = sum;
  __syncthreads();
  sum = rsum[0] + rsum[1] + rsum[2] + rsum[3];
  float inv = 1.f / sum;
#pragma unroll
  for (int i = 0; i < 4; i++) {
    float4 o = v[i];
    o.x *= inv; o.y *= inv; o.z *= inv; o.w *= inv;
    *(float4*)(p + (i * 256 + tid) * 4) = o;
  }
}

// ---------------- attn @ V (partials over 4 j-chunks) ----------------
// grid = 4 jc * 8 g * 8 dblk = 256 blocks, 256 threads (64 qrow x 4 dq)
__global__ __launch_bounds__(256) void pv_kernel(const float* __restrict__ attn,
                                                 const float* __restrict__ cv,
                                                 const float* __restrict__ nv,
                                                 float* __restrict__ part) {
  int bx = blockIdx.x;
  int jc = bx >> 6;
  int g = (bx >> 3) & 7;
  int dblk = bx & 7;
  int qrow = threadIdx.x & 63;
  int dq = threadIdx.x >> 6;
  int d = dblk * 16 + dq * 4;
  __shared__ float sA[64][132];
  float4 acc = make_float4(0.f, 0.f, 0.f, 0.f);
  for (int js = 0; js < 8; js++) {
    int jbase = jc * 1024 + js * 128;
#pragma unroll
    for (int i = 0; i < 8; i++) {
      int idx4 = i * 256 + threadIdx.x;
      int row = idx4 >> 5;
      int c4 = idx4 & 31;
      float4 a4 = ld4(attn + ((size_t)g * 64 + row) * TTOT + jbase + c4 * 4);
      *(float4*)&sA[row][c4 * 4] = a4;
    }
    __syncthreads();
#pragma unroll 2
    for (int jj = 0; jj < 128; jj += 4) {
      float4 a4 = *(const float4*)&sA[qrow][jj];
      int j = jbase + jj;
      {
        const float* vp = (j + 0 < TCACHE) ? cv + ((size_t)g * TCACHE + j + 0) * 128 + d
                                           : nv + ((size_t)g * 16 + (j + 0 - TCACHE)) * 128 + d;
        float4 v4 = ld4(vp);
        acc.x += a4.x * v4.x; acc.y += a4.x * v4.y; acc.z += a4.x * v4.z; acc.w += a4.x * v4.w;
      }
      {
        const float* vp = (j + 1 < TCACHE) ? cv + ((size_t)g * TCACHE + j + 1) * 128 + d
                                           : nv + ((size_t)g * 16 + (j + 1 - TCACHE)) * 128 + d;
        float4 v4 = ld4(vp);
        acc.x += a4.y * v4.x; acc.y += a4.y * v4.y; acc.z += a4.y * v4.z; acc.w += a4.y * v4.w;
      }
      {
        const float* vp = (j + 2 < TCACHE) ? cv + ((size_t)g * TCACHE + j + 2) * 128 + d
                                           : nv + ((size_t)g * 16 + (j + 2 - TCACHE)) * 128 + d;
        float4 v4 = ld4(vp);
        acc.x += a4.z * v4.x; acc.y += a4.z * v4.y; acc.z += a4.z * v4.z; acc.w += a4.z * v4.w;
      }
      {
        const float* vp = (j + 3 < TCACHE) ? cv + ((size_t)g * TCACHE + j + 3) * 128 + d
                                           : nv + ((size_t)g * 16 + (j + 3 - TCACHE)) * 128 + d;
        float4 v4 = ld4(vp);
        acc.x += a4.w * v4.x; acc.y += a4.w * v4.y; acc.z += a4.w * v4.z; acc.w += a4.w * v4.w;
      }
    }
    __syncthreads();
  }
  *(float4*)&part[(size_t)jc * 65536 + ((size_t)g * 64 + qrow) * 128 + d] = acc;
}

// ---------------- reduce pv partials + flatten to [t][h*128+d] ----------------
__global__ void pv_reduce_kernel(const float* __restrict__ pp, float* __restrict__ aflat) {
  int idx = blockIdx.x * 256 + threadIdx.x;  // 0..65535, = (h*16+t)*128 + d
  float s = pp[idx] + pp[65536 + idx] + pp[131072 + idx] + pp[196608 + idx];
  int hh = idx >> 11;
  int t = (idx >> 7) & 15;
  int dd = idx & 127;
  aflat[(size_t)t * QDIM + hh * 128 + dd] = s;
}

// ---------------- generic split-K projection: out[chunk][t][o] ----------------
__global__ void proj_kernel(const float* __restrict__ A, const float* __restrict__ W,
                            float* __restrict__ out, int N, int K, int klen, int bpc) {
  int t = threadIdx.x & 15;
  int osub = threadIdx.x >> 4;
  int chunk = blockIdx.x / bpc;
  int brow = blockIdx.x % bpc;
  int o = brow * 8 + osub;
  int k0 = chunk * klen;
  const float* a = A + (size_t)t * K + k0;
  const float* wp = W + (size_t)o * K + k0;
  float acc = 0.f;
#pragma unroll 4
  for (int k = 0; k < klen; k += 4) {
    float4 w4 = ld4(wp + k);
    float4 a4 = ld4(a + k);
    acc += w4.x * a4.x + w4.y * a4.y + w4.z * a4.z + w4.w * a4.w;
  }
  out[(size_t)chunk * 16 * N + (size_t)t * N + o] = acc;
}

// ---------------- h = x + o_part0 + o_part1 ; y2 = rmsnorm(h) ----------------
__global__ void resid_rms_kernel(const float* __restrict__ x, const float* __restrict__ p,
                                 const float* __restrict__ w, float* __restrict__ h,
                                 float* __restrict__ y2) {
  int t = blockIdx.x;
  int tid = threadIdx.x;
  float v[10];
  float ss = 0.f;
#pragma unroll
  for (int i = 0; i < 10; i++) {
    int idx = i * 256 + tid;
    size_t gidx = (size_t)t * HIDDEN + idx;
    float hv = x[gidx] + p[gidx] + p[40960 + gidx];
    h[gidx] = hv;
    v[i] = hv;
    ss += hv * hv;
  }
#pragma unroll
  for (int off = 32; off > 0; off >>= 1) ss += __shfl_down(ss, off, 64);
  __shared__ float sred[4];
  if ((tid & 63) == 0) sred[tid >> 6] = ss;
  __syncthreads();
  ss = sred[0] + sred[1] + sred[2] + sred[3];
  float r = rsqrtf(ss / (float)HIDDEN + 1e-6f);
#pragma unroll
  for (int i = 0; i < 10; i++) {
    int idx = i * 256 + tid;
    y2[(size_t)t * HIDDEN + idx] = v[i] * r * w[idx];
  }
}

// ---------------- fused gate/up + silu*up ----------------
__global__ void gateup_kernel(const float* __restrict__ y2, const float* __restrict__ gw,
                              const float* __restrict__ uw, float* __restrict__ act) {
  int t = threadIdx.x & 15;
  int osub = threadIdx.x >> 4;
  int o = blockIdx.x * 8 + osub;
  const float* a = y2 + (size_t)t * HIDDEN;
  const float* gp = gw + (size_t)o * HIDDEN;
  const float* up = uw + (size_t)o * HIDDEN;
  float ag = 0.f, au = 0.f;
#pragma unroll 4
  for (int k = 0; k < HIDDEN; k += 4) {
    float4 a4 = ld4(a + k);
    float4 g4 = ld4(gp + k);
    float4 u4 = ld4(up + k);
    ag += g4.x * a4.x + g4.y * a4.y + g4.z * a4.z + g4.w * a4.w;
    au += u4.x * a4.x + u4.y * a4.y + u4.z * a4.z + u4.w * a4.w;
  }
  float s = ag / (1.f + __expf(-ag));
  act[(size_t)t * INTER + o] = s * au;
}

// ---------------- out0 = h + sum(down partials) ----------------
__global__ void final_kernel(const float* __restrict__ h, const float* __restrict__ dp,
                             float* __restrict__ out) {
  int idx = blockIdx.x * 256 + threadIdx.x;  // 40960
  out[idx] = h[idx] + dp[idx] + dp[40960 + idx] + dp[81920 + idx] + dp[122880 + idx];
}

extern "C" void kernel_launch(void* const* d_in, const int* in_sizes, int n_in,
                              void* d_out, int out_size, void* d_ws, size_t ws_size,
                              hipStream_t stream) {
  const float* x       = (const float*)d_in[0];
  const float* cos_q   = (const float*)d_in[1];
  const float* sin_q   = (const float*)d_in[2];
  const float* cos_k   = (const float*)d_in[3];
  const float* sin_k   = (const float*)d_in[4];
  const float* cache_k = (const float*)d_in[5];
  const float* cache_v = (const float*)d_in[6];
  const float* mask    = (const float*)d_in[7];
  const float* iln     = (const float*)d_in[8];
  const float* pln     = (const float*)d_in[9];
  const float* qnw     = (const float*)d_in[10];
  const float* knw     = (const float*)d_in[11];
  const float* qw      = (const float*)d_in[12];
  const float* kw      = (const float*)d_in[13];
  const float* vw      = (const float*)d_in[14];
  const float* ow      = (const float*)d_in[15];
  const float* gw      = (const float*)d_in[16];
  const float* uw      = (const float*)d_in[17];
  const float* dw      = (const float*)d_in[18];

  float* out0 = (float*)d_out;
  float* outk = out0 + 40960;
  float* outv = out0 + 57344;

  float* ws    = (float*)d_ws;
  float* y     = ws;                  // 40960
  float* q_ws  = y + 40960;           // 2*65536
  float* k_ws  = q_ws + 131072;       // 2*16384
  float* v_ws  = k_ws + 32768;        // 2*16384
  float* q_r   = v_ws + 32768;        // 65536
  float* sc    = q_r + 65536;         // 2097152
  float* pvp   = sc + 2097152;        // 4*65536
  float* aflat = pvp + 262144;        // 65536
  float* opart = aflat + 65536;       // 2*40960
  float* h     = opart + 81920;       // 40960
  float* y2    = h + 40960;           // 40960
  float* act   = y2 + 40960;          // 155648
  float* dpart = act + 155648;        // 4*40960

  rms_kernel<<<16, 256, 0, stream>>>(x, iln, y);
  qkv_kernel<<<1536, 128, 0, stream>>>(y, qw, kw, vw, q_ws, k_ws, v_ws);
  normrope_kernel<<<648, 128, 0, stream>>>(q_ws, k_ws, v_ws, qnw, knw, cos_q, sin_q,
                                           cos_k, sin_k, q_r, outk, outv);
  scores_kernel<<<512, 256, 0, stream>>>(q_r, cache_k, outk, mask, sc);
  softmax_kernel<<<512, 256, 0, stream>>>(sc);
  pv_kernel<<<256, 256, 0, stream>>>(sc, cache_v, outv, pvp);
  pv_reduce_kernel<<<256, 256, 0, stream>>>(pvp, aflat);
  proj_kernel<<<640, 128, 0, stream>>>(aflat, ow, opart, 2560, 4096, 2048, 320);
  resid_rms_kernel<<<16, 256, 0, stream>>>(x, opart, pln, h, y2);
  gateup_kernel<<<1216, 128, 0, stream>>>(y2, gw, uw, act);
  proj_kernel<<<1280, 128, 0, stream>>>(act, dw, dpart, 2560, 9728, 2432, 320);
  final_kernel<<<160, 256, 0, stream>>>(h, dpart, out0);
}

// Round 2
// 672.932 us; speedup vs baseline: 1.7900x; 1.7900x over previous
//
#include <hip/hip_runtime.h>
#include <math.h>

#define HIDDEN 2560
#define HEAD_DIM 128
#define NH 32
#define NKV 8
#define TNEW 16
#define TCACHE 4080
#define TTOT 4096
#define INTER 9728
#define QDIM 4096
#define KVDIM 1024

static __device__ __forceinline__ float4 ld4(const float* p){ return *(const float4*)p; }

// ================= coalesced 16-token GEMV =================
// Wave: 4 output rows x 16 tokens. Lane L covers k = k0 + L*4 (+256 per k-block).
// Block 256 threads = 4 waves = 16 rows. grid = nchunk * bpc, bpc = N/16.
// out[chunk][t][N]. chunk_len and K multiples of 256 after min().
__device__ __forceinline__ void gemv16_body(const float* __restrict__ A,
                                            const float* __restrict__ W,
                                            float* __restrict__ out,
                                            int N, int K, int k0, int klen,
                                            int row0, int chunk) {
  int lane = threadIdx.x & 63;
  const float* a0 = A + k0 + lane * 4;
  const float* w0 = W + (size_t)row0 * K + k0 + lane * 4;
  float acc[4][16];
#pragma unroll
  for (int r = 0; r < 4; r++)
#pragma unroll
    for (int t = 0; t < 16; t++) acc[r][t] = 0.f;

  for (int kb = 0; kb < klen; kb += 256) {
    float4 w4[4];
#pragma unroll
    for (int r = 0; r < 4; r++) w4[r] = ld4(w0 + (size_t)r * K + kb);
#pragma unroll
    for (int t = 0; t < 16; t++) {
      float4 a4 = ld4(a0 + (size_t)t * K + kb);
#pragma unroll
      for (int r = 0; r < 4; r++)
        acc[r][t] += w4[r].x * a4.x + w4[r].y * a4.y + w4[r].z * a4.z + w4[r].w * a4.w;
    }
  }
  // recursive-halving reduce with output distribution: lane L ends with
  // output j = L, i.e. r = L>>4, t = L&15.
  float v[64];
#pragma unroll
  for (int r = 0; r < 4; r++)
#pragma unroll
    for (int t = 0; t < 16; t++) v[r * 16 + t] = acc[r][t];
#pragma unroll
  for (int s = 5; s >= 0; s--) {
    int m = 1 << s;
    bool hi = (lane & m) != 0;
#pragma unroll
    for (int i = 0; i < 64; i++) {
      if (i < m) {
        float keep = hi ? v[i + m] : v[i];
        float send = hi ? v[i] : v[i + m];
        v[i] = keep + __shfl_xor(send, m, 64);
      }
    }
  }
  int r = lane >> 4, t = lane & 15;
  out[(size_t)chunk * 16 * N + (size_t)t * N + row0 + r] = v[0];
}

__global__ __launch_bounds__(256) void gemv16_kernel(const float* __restrict__ A,
                                                     const float* __restrict__ W,
                                                     float* __restrict__ out,
                                                     int N, int K, int chunk_len, int bpc) {
  int wave = threadIdx.x >> 6;
  int chunk = blockIdx.x / bpc;
  int brow = blockIdx.x % bpc;
  int row0 = brow * 16 + wave * 4;
  int k0 = chunk * chunk_len;
  int klen = min(chunk_len, K - k0);
  gemv16_body(A, W, out, N, K, k0, klen, row0, chunk);
}

// fused gate/up: blocks [0,608) -> gate rows, [608,1216) -> up rows; full K.
__global__ __launch_bounds__(256) void gateup16_kernel(const float* __restrict__ A,
                                                       const float* __restrict__ gw,
                                                       const float* __restrict__ uw,
                                                       float* __restrict__ outg,
                                                       float* __restrict__ outu) {
  int wave = threadIdx.x >> 6;
  int b = blockIdx.x;
  const float* W = (b < 608) ? gw : uw;
  float* out = (b < 608) ? outg : outu;
  int brow = (b < 608) ? b : b - 608;
  int row0 = brow * 16 + wave * 4;
  gemv16_body(A, W, out, INTER, HIDDEN, 0, HIDDEN, row0, 0);
}

__global__ void silu_kernel(const float* __restrict__ g, const float* __restrict__ u,
                            float* __restrict__ act) {
  int idx = blockIdx.x * 256 + threadIdx.x;  // 155648
  float gv = g[idx];
  act[idx] = (gv / (1.f + __expf(-gv))) * u[idx];
}

// ---------------- RMSNorm over x (16 x 2560) ----------------
__global__ void rms_kernel(const float* __restrict__ x, const float* __restrict__ w,
                           float* __restrict__ y) {
  int t = blockIdx.x;
  int tid = threadIdx.x;
  const float* xp = x + (size_t)t * HIDDEN;
  float v[10];
  float ss = 0.f;
#pragma unroll
  for (int i = 0; i < 10; i++) { v[i] = xp[i * 256 + tid]; ss += v[i] * v[i]; }
#pragma unroll
  for (int off = 32; off > 0; off >>= 1) ss += __shfl_down(ss, off, 64);
  __shared__ float sred[4];
  if ((tid & 63) == 0) sred[tid >> 6] = ss;
  __syncthreads();
  ss = sred[0] + sred[1] + sred[2] + sred[3];
  float r = rsqrtf(ss / (float)HIDDEN + 1e-6f);
  float* yp = y + (size_t)t * HIDDEN;
#pragma unroll
  for (int i = 0; i < 10; i++) yp[i * 256 + tid] = v[i] * r * w[i * 256 + tid];
}

// ---------------- q/k rmsnorm + rope, v copy ----------------
__global__ void normrope_kernel(const float* __restrict__ q_ws, const float* __restrict__ k_ws,
                                const float* __restrict__ v_ws,
                                const float* __restrict__ qnw, const float* __restrict__ knw,
                                const float* __restrict__ cosq, const float* __restrict__ sinq,
                                const float* __restrict__ cosk, const float* __restrict__ sink,
                                float* __restrict__ q_r, float* __restrict__ out_k,
                                float* __restrict__ out_v) {
  int b = blockIdx.x;
  int d = threadIdx.x;
  __shared__ float sn[128];
  __shared__ float sred[2];
  if (b < 640) {
    float val; const float* nw; int t;
    if (b < 512) {
      int h = b >> 4; t = b & 15;
      size_t idx = (size_t)t * QDIM + h * HEAD_DIM + d;
      val = q_ws[idx] + q_ws[65536 + idx];
      nw = qnw;
    } else {
      int g = (b - 512) >> 4; t = (b - 512) & 15;
      size_t idx = (size_t)t * KVDIM + g * HEAD_DIM + d;
      val = k_ws[idx] + k_ws[16384 + idx];
      nw = knw;
    }
    float ss = val * val;
#pragma unroll
    for (int off = 32; off > 0; off >>= 1) ss += __shfl_down(ss, off, 64);
    if ((d & 63) == 0) sred[d >> 6] = ss;
    __syncthreads();
    ss = sred[0] + sred[1];
    float r = rsqrtf(ss / 128.f + 1e-6f);
    float n = val * r * nw[d];
    sn[d] = n;
    __syncthreads();
    float rot = (d < 64) ? -sn[d + 64] : sn[d - 64];
    const float* C = (b < 512) ? cosq : cosk;
    const float* S = (b < 512) ? sinq : sink;
    float res = n * C[t * 128 + d] + rot * S[t * 128 + d];
    if (b < 512) {
      int h = b >> 4;
      q_r[((size_t)(h * 16 + t)) * 128 + d] = res;
    } else {
      int g = (b - 512) >> 4;
      out_k[((size_t)(g * 16 + t)) * 128 + d] = res;
    }
  } else {
    int bb = b - 640;
#pragma unroll
    for (int i = 0; i < 16; i++) {
      int idx = bb * 2048 + i * 128 + d;  // [g][t][d]
      int g = idx >> 11; int t2 = (idx >> 7) & 15; int dd = idx & 127;
      size_t sidx = (size_t)t2 * KVDIM + g * HEAD_DIM + dd;
      out_v[idx] = v_ws[sidx] + v_ws[16384 + sidx];
    }
  }
}

// ---------------- scores = q @ K^T * scale + mask ----------------
__global__ __launch_bounds__(256) void scores_kernel(const float* __restrict__ q_r,
                                                     const float* __restrict__ ck,
                                                     const float* __restrict__ nk,
                                                     const float* __restrict__ mask,
                                                     float* __restrict__ sc) {
  int g = blockIdx.x >> 6;
  int jblk = blockIdx.x & 63;
  int lane = threadIdx.x & 63;  // qrow = hsub*16 + t
  int wv = threadIdx.x >> 6;
  const float* qp = q_r + ((size_t)g * 64 + lane) * 128;
  float4 qreg[32];
#pragma unroll
  for (int i = 0; i < 32; i++) qreg[i] = ld4(qp + i * 4);
  int t = lane & 15;
  const float scale = 0.08838834764831845f;
  for (int jj = 0; jj < 16; jj++) {
    int j = jblk * 64 + jj * 4 + wv;
    const float* kp = (j < TCACHE) ? ck + ((size_t)g * TCACHE + j) * 128
                                   : nk + ((size_t)g * 16 + (j - TCACHE)) * 128;
    float acc = 0.f;
#pragma unroll
    for (int i = 0; i < 32; i++) {
      float4 k4 = ld4(kp + i * 4);
      acc += qreg[i].x * k4.x + qreg[i].y * k4.y + qreg[i].z * k4.z + qreg[i].w * k4.w;
    }
    sc[((size_t)g * 64 + lane) * TTOT + j] = acc * scale + mask[t * TTOT + j];
  }
}

// ---------------- softmax over 4096, one block per (h,t) row ----------------
__global__ void softmax_kernel(float* __restrict__ sc) {
  int row = blockIdx.x;
  int tid = threadIdx.x;
  float* p = sc + (size_t)row * TTOT;
  float4 v[4];
  float mx = -1e30f;
#pragma unroll
  for (int i = 0; i < 4; i++) {
    v[i] = ld4(p + (i * 256 + tid) * 4);
    mx = fmaxf(mx, fmaxf(fmaxf(v[i].x, v[i].y), fmaxf(v[i].z, v[i].w)));
  }
#pragma unroll
  for (int off = 32; off > 0; off >>= 1) mx = fmaxf(mx, __shfl_down(mx, off, 64));
  __shared__ float rmax[4], rsum[4];
  if ((tid & 63) == 0) rmax[tid >> 6] = mx;
  __syncthreads();
  mx = fmaxf(fmaxf(rmax[0], rmax[1]), fmaxf(rmax[2], rmax[3]));
  float sum = 0.f;
#pragma unroll
  for (int i = 0; i < 4; i++) {
    v[i].x = __expf(v[i].x - mx); v[i].y = __expf(v[i].y - mx);
    v[i].z = __expf(v[i].z - mx); v[i].w = __expf(v[i].w - mx);
    sum += v[i].x + v[i].y + v[i].z + v[i].w;
  }
#pragma unroll
  for (int off = 32; off > 0; off >>= 1) sum += __shfl_down(sum, off, 64);
  if ((tid & 63) == 0) rsum[tid >> 6] = sum;
  __syncthreads();
  sum = rsum[0] + rsum[1] + rsum[2] + rsum[3];
  float inv = 1.f / sum;
#pragma unroll
  for (int i = 0; i < 4; i++) {
    float4 o = v[i];
    o.x *= inv; o.y *= inv; o.z *= inv; o.w *= inv;
    *(float4*)(p + (i * 256 + tid) * 4) = o;
  }
}

// ---------------- attn @ V (partials over 4 j-chunks) ----------------
__global__ __launch_bounds__(256) void pv_kernel(const float* __restrict__ attn,
                                                 const float* __restrict__ cv,
                                                 const float* __restrict__ nv,
                                                 float* __restrict__ part) {
  int bx = blockIdx.x;
  int jc = bx >> 6;
  int g = (bx >> 3) & 7;
  int dblk = bx & 7;
  int qrow = threadIdx.x & 63;
  int dq = threadIdx.x >> 6;
  int d = dblk * 16 + dq * 4;
  __shared__ float sA[64][132];
  float4 acc = make_float4(0.f, 0.f, 0.f, 0.f);
  for (int js = 0; js < 8; js++) {
    int jbase = jc * 1024 + js * 128;
#pragma unroll
    for (int i = 0; i < 8; i++) {
      int idx4 = i * 256 + threadIdx.x;
      int row = idx4 >> 5;
      int c4 = idx4 & 31;
      float4 a4 = ld4(attn + ((size_t)g * 64 + row) * TTOT + jbase + c4 * 4);
      *(float4*)&sA[row][c4 * 4] = a4;
    }
    __syncthreads();
#pragma unroll 2
    for (int jj = 0; jj < 128; jj += 4) {
      float4 a4 = *(const float4*)&sA[qrow][jj];
      int j = jbase + jj;
      {
        const float* vp = (j + 0 < TCACHE) ? cv + ((size_t)g * TCACHE + j + 0) * 128 + d
                                           : nv + ((size_t)g * 16 + (j + 0 - TCACHE)) * 128 + d;
        float4 v4 = ld4(vp);
        acc.x += a4.x * v4.x; acc.y += a4.x * v4.y; acc.z += a4.x * v4.z; acc.w += a4.x * v4.w;
      }
      {
        const float* vp = (j + 1 < TCACHE) ? cv + ((size_t)g * TCACHE + j + 1) * 128 + d
                                           : nv + ((size_t)g * 16 + (j + 1 - TCACHE)) * 128 + d;
        float4 v4 = ld4(vp);
        acc.x += a4.y * v4.x; acc.y += a4.y * v4.y; acc.z += a4.y * v4.z; acc.w += a4.y * v4.w;
      }
      {
        const float* vp = (j + 2 < TCACHE) ? cv + ((size_t)g * TCACHE + j + 2) * 128 + d
                                           : nv + ((size_t)g * 16 + (j + 2 - TCACHE)) * 128 + d;
        float4 v4 = ld4(vp);
        acc.x += a4.z * v4.x; acc.y += a4.z * v4.y; acc.z += a4.z * v4.z; acc.w += a4.z * v4.w;
      }
      {
        const float* vp = (j + 3 < TCACHE) ? cv + ((size_t)g * TCACHE + j + 3) * 128 + d
                                           : nv + ((size_t)g * 16 + (j + 3 - TCACHE)) * 128 + d;
        float4 v4 = ld4(vp);
        acc.x += a4.w * v4.x; acc.y += a4.w * v4.y; acc.z += a4.w * v4.z; acc.w += a4.w * v4.w;
      }
    }
    __syncthreads();
  }
  *(float4*)&part[(size_t)jc * 65536 + ((size_t)g * 64 + qrow) * 128 + d] = acc;
}

// ---------------- reduce pv partials + flatten to [t][h*128+d] ----------------
__global__ void pv_reduce_kernel(const float* __restrict__ pp, float* __restrict__ aflat) {
  int idx = blockIdx.x * 256 + threadIdx.x;  // 0..65535, = (h*16+t)*128 + d
  float s = pp[idx] + pp[65536 + idx] + pp[131072 + idx] + pp[196608 + idx];
  int hh = idx >> 11;
  int t = (idx >> 7) & 15;
  int dd = idx & 127;
  aflat[(size_t)t * QDIM + hh * 128 + dd] = s;
}

// ---------------- h = x + sum of 4 o-partials ; y2 = rmsnorm(h) ----------------
__global__ void resid_rms_kernel(const float* __restrict__ x, const float* __restrict__ p,
                                 const float* __restrict__ w, float* __restrict__ h,
                                 float* __restrict__ y2) {
  int t = blockIdx.x;
  int tid = threadIdx.x;
  float v[10];
  float ss = 0.f;
#pragma unroll
  for (int i = 0; i < 10; i++) {
    int idx = i * 256 + tid;
    size_t gidx = (size_t)t * HIDDEN + idx;
    float hv = x[gidx] + p[gidx] + p[40960 + gidx] + p[81920 + gidx] + p[122880 + gidx];
    h[gidx] = hv;
    v[i] = hv;
    ss += hv * hv;
  }
#pragma unroll
  for (int off = 32; off > 0; off >>= 1) ss += __shfl_down(ss, off, 64);
  __shared__ float sred[4];
  if ((tid & 63) == 0) sred[tid >> 6] = ss;
  __syncthreads();
  ss = sred[0] + sred[1] + sred[2] + sred[3];
  float r = rsqrtf(ss / (float)HIDDEN + 1e-6f);
#pragma unroll
  for (int i = 0; i < 10; i++) {
    int idx = i * 256 + tid;
    y2[(size_t)t * HIDDEN + idx] = v[i] * r * w[idx];
  }
}

// ---------------- out0 = h + sum(down partials) ----------------
__global__ void final_kernel(const float* __restrict__ h, const float* __restrict__ dp,
                             float* __restrict__ out) {
  int idx = blockIdx.x * 256 + threadIdx.x;  // 40960
  out[idx] = h[idx] + dp[idx] + dp[40960 + idx] + dp[81920 + idx] + dp[122880 + idx];
}

extern "C" void kernel_launch(void* const* d_in, const int* in_sizes, int n_in,
                              void* d_out, int out_size, void* d_ws, size_t ws_size,
                              hipStream_t stream) {
  const float* x       = (const float*)d_in[0];
  const float* cos_q   = (const float*)d_in[1];
  const float* sin_q   = (const float*)d_in[2];
  const float* cos_k   = (const float*)d_in[3];
  const float* sin_k   = (const float*)d_in[4];
  const float* cache_k = (const float*)d_in[5];
  const float* cache_v = (const float*)d_in[6];
  const float* mask    = (const float*)d_in[7];
  const float* iln     = (const float*)d_in[8];
  const float* pln     = (const float*)d_in[9];
  const float* qnw     = (const float*)d_in[10];
  const float* knw     = (const float*)d_in[11];
  const float* qw      = (const float*)d_in[12];
  const float* kw      = (const float*)d_in[13];
  const float* vw      = (const float*)d_in[14];
  const float* ow      = (const float*)d_in[15];
  const float* gw      = (const float*)d_in[16];
  const float* uw      = (const float*)d_in[17];
  const float* dw      = (const float*)d_in[18];

  float* out0 = (float*)d_out;
  float* outk = out0 + 40960;
  float* outv = out0 + 57344;

  float* ws    = (float*)d_ws;
  float* y     = ws;                  // 40960
  float* q_ws  = y + 40960;           // 2*65536
  float* k_ws  = q_ws + 131072;       // 2*16384
  float* v_ws  = k_ws + 32768;        // 2*16384
  float* q_r   = v_ws + 32768;        // 65536
  float* sc    = q_r + 65536;         // 2097152
  float* pvp   = sc + 2097152;        // 4*65536
  float* aflat = pvp + 262144;        // 65536
  float* opart = aflat + 65536;       // 4*40960
  float* h     = opart + 163840;      // 40960
  float* y2    = h + 40960;           // 40960
  // overlap with sc (dead after pv_kernel):
  float* g_tmp = sc;                  // 155648
  float* u_tmp = sc + 155648;         // 155648
  float* act   = sc + 311296;         // 155648
  float* dpart = sc + 466944;         // 4*40960

  rms_kernel<<<16, 256, 0, stream>>>(x, iln, y);
  gemv16_kernel<<<512, 256, 0, stream>>>(y, qw, q_ws, QDIM, HIDDEN, 1280, 256);
  gemv16_kernel<<<128, 256, 0, stream>>>(y, kw, k_ws, KVDIM, HIDDEN, 1280, 64);
  gemv16_kernel<<<128, 256, 0, stream>>>(y, vw, v_ws, KVDIM, HIDDEN, 1280, 64);
  normrope_kernel<<<648, 128, 0, stream>>>(q_ws, k_ws, v_ws, qnw, knw, cos_q, sin_q,
                                           cos_k, sin_k, q_r, outk, outv);
  scores_kernel<<<512, 256, 0, stream>>>(q_r, cache_k, outk, mask, sc);
  softmax_kernel<<<512, 256, 0, stream>>>(sc);
  pv_kernel<<<256, 256, 0, stream>>>(sc, cache_v, outv, pvp);
  pv_reduce_kernel<<<256, 256, 0, stream>>>(pvp, aflat);
  gemv16_kernel<<<640, 256, 0, stream>>>(aflat, ow, opart, HIDDEN, QDIM, 1024, 160);
  resid_rms_kernel<<<16, 256, 0, stream>>>(x, opart, pln, h, y2);
  gateup16_kernel<<<1216, 256, 0, stream>>>(y2, gw, uw, g_tmp, u_tmp);
  silu_kernel<<<608, 256, 0, stream>>>(g_tmp, u_tmp, act);
  gemv16_kernel<<<640, 256, 0, stream>>>(act, dw, dpart, HIDDEN, INTER, 2560, 160);
  final_kernel<<<160, 256, 0, stream>>>(h, dpart, out0);
}

// Round 3
// 560.533 us; speedup vs baseline: 2.1490x; 1.2005x over previous
//
#include <hip/hip_runtime.h>
#include <math.h>

#define HIDDEN 2560
#define HEAD_DIM 128
#define NH 32
#define NKV 8
#define TNEW 16
#define TCACHE 4080
#define TTOT 4096
#define INTER 9728
#define QDIM 4096
#define KVDIM 1024

static __device__ __forceinline__ float4 ld4(const float* p){ return *(const float4*)p; }

// ================= coalesced 16-token GEMV =================
// Wave: 4 output rows x 16 tokens. Lane L covers k = k0 + L*4 (+256 per k-block).
// Weight loads double-buffered to cover HBM latency.
__device__ __forceinline__ void gemv16_body(const float* __restrict__ A,
                                            const float* __restrict__ W,
                                            float* __restrict__ out,
                                            int N, int K, int k0, int klen,
                                            int row0, int chunk) {
  int lane = threadIdx.x & 63;
  const float* a0 = A + k0 + lane * 4;
  const float* w0 = W + (size_t)row0 * K + k0 + lane * 4;
  float acc[4][16];
#pragma unroll
  for (int r = 0; r < 4; r++)
#pragma unroll
    for (int t = 0; t < 16; t++) acc[r][t] = 0.f;

  float4 wc[4];
#pragma unroll
  for (int r = 0; r < 4; r++) wc[r] = ld4(w0 + (size_t)r * K);

  for (int kb = 0; kb < klen; kb += 256) {
    float4 wn[4];
    int kn = kb + 256;
    if (kn < klen) {
#pragma unroll
      for (int r = 0; r < 4; r++) wn[r] = ld4(w0 + (size_t)r * K + kn);
    } else {
#pragma unroll
      for (int r = 0; r < 4; r++) wn[r] = wc[r];
    }
#pragma unroll
    for (int t = 0; t < 16; t++) {
      float4 a4 = ld4(a0 + (size_t)t * K + kb);
#pragma unroll
      for (int r = 0; r < 4; r++)
        acc[r][t] += wc[r].x * a4.x + wc[r].y * a4.y + wc[r].z * a4.z + wc[r].w * a4.w;
    }
#pragma unroll
    for (int r = 0; r < 4; r++) wc[r] = wn[r];
  }
  // recursive-halving reduce with output distribution: lane L ends with output L.
  float v[64];
#pragma unroll
  for (int r = 0; r < 4; r++)
#pragma unroll
    for (int t = 0; t < 16; t++) v[r * 16 + t] = acc[r][t];
#pragma unroll
  for (int s = 5; s >= 0; s--) {
    int m = 1 << s;
    bool hi = (lane & m) != 0;
#pragma unroll
    for (int i = 0; i < 64; i++) {
      if (i < m) {
        float keep = hi ? v[i + m] : v[i];
        float send = hi ? v[i] : v[i + m];
        v[i] = keep + __shfl_xor(send, m, 64);
      }
    }
  }
  int r = lane >> 4, t = lane & 15;
  out[(size_t)chunk * 16 * N + (size_t)t * N + row0 + r] = v[0];
}

__global__ __launch_bounds__(256) void gemv16_kernel(const float* __restrict__ A,
                                                     const float* __restrict__ W,
                                                     float* __restrict__ out,
                                                     int N, int K, int chunk_len, int bpc) {
  int wave = threadIdx.x >> 6;
  int chunk = blockIdx.x / bpc;
  int brow = blockIdx.x % bpc;
  int row0 = brow * 16 + wave * 4;
  int k0 = chunk * chunk_len;
  int klen = min(chunk_len, K - k0);
  gemv16_body(A, W, out, N, K, k0, klen, row0, chunk);
}

__global__ __launch_bounds__(256) void gateup16_kernel(const float* __restrict__ A,
                                                       const float* __restrict__ gw,
                                                       const float* __restrict__ uw,
                                                       float* __restrict__ outg,
                                                       float* __restrict__ outu) {
  int wave = threadIdx.x >> 6;
  int b = blockIdx.x;
  const float* W = (b < 608) ? gw : uw;
  float* out = (b < 608) ? outg : outu;
  int brow = (b < 608) ? b : b - 608;
  int row0 = brow * 16 + wave * 4;
  gemv16_body(A, W, out, INTER, HIDDEN, 0, HIDDEN, row0, 0);
}

__global__ void silu_kernel(const float* __restrict__ g, const float* __restrict__ u,
                            float* __restrict__ act) {
  int idx = blockIdx.x * 256 + threadIdx.x;  // 155648
  float gv = g[idx];
  act[idx] = (gv / (1.f + __expf(-gv))) * u[idx];
}

// ---------------- RMSNorm over x (16 x 2560) ----------------
__global__ void rms_kernel(const float* __restrict__ x, const float* __restrict__ w,
                           float* __restrict__ y) {
  int t = blockIdx.x;
  int tid = threadIdx.x;
  const float* xp = x + (size_t)t * HIDDEN;
  float v[10];
  float ss = 0.f;
#pragma unroll
  for (int i = 0; i < 10; i++) { v[i] = xp[i * 256 + tid]; ss += v[i] * v[i]; }
#pragma unroll
  for (int off = 32; off > 0; off >>= 1) ss += __shfl_down(ss, off, 64);
  __shared__ float sred[4];
  if ((tid & 63) == 0) sred[tid >> 6] = ss;
  __syncthreads();
  ss = sred[0] + sred[1] + sred[2] + sred[3];
  float r = rsqrtf(ss / (float)HIDDEN + 1e-6f);
  float* yp = y + (size_t)t * HIDDEN;
#pragma unroll
  for (int i = 0; i < 10; i++) yp[i * 256 + tid] = v[i] * r * w[i * 256 + tid];
}

// ---------------- q/k rmsnorm + rope, v copy ----------------
__global__ void normrope_kernel(const float* __restrict__ q_ws, const float* __restrict__ k_ws,
                                const float* __restrict__ v_ws,
                                const float* __restrict__ qnw, const float* __restrict__ knw,
                                const float* __restrict__ cosq, const float* __restrict__ sinq,
                                const float* __restrict__ cosk, const float* __restrict__ sink,
                                float* __restrict__ q_r, float* __restrict__ out_k,
                                float* __restrict__ out_v) {
  int b = blockIdx.x;
  int d = threadIdx.x;
  __shared__ float sn[128];
  __shared__ float sred[2];
  if (b < 640) {
    float val; const float* nw; int t;
    if (b < 512) {
      int h = b >> 4; t = b & 15;
      size_t idx = (size_t)t * QDIM + h * HEAD_DIM + d;
      val = q_ws[idx] + q_ws[65536 + idx];
      nw = qnw;
    } else {
      int g = (b - 512) >> 4; t = (b - 512) & 15;
      size_t idx = (size_t)t * KVDIM + g * HEAD_DIM + d;
      val = k_ws[idx] + k_ws[16384 + idx];
      nw = knw;
    }
    float ss = val * val;
#pragma unroll
    for (int off = 32; off > 0; off >>= 1) ss += __shfl_down(ss, off, 64);
    if ((d & 63) == 0) sred[d >> 6] = ss;
    __syncthreads();
    ss = sred[0] + sred[1];
    float r = rsqrtf(ss / 128.f + 1e-6f);
    float n = val * r * nw[d];
    sn[d] = n;
    __syncthreads();
    float rot = (d < 64) ? -sn[d + 64] : sn[d - 64];
    const float* C = (b < 512) ? cosq : cosk;
    const float* S = (b < 512) ? sinq : sink;
    float res = n * C[t * 128 + d] + rot * S[t * 128 + d];
    if (b < 512) {
      int h = b >> 4;
      q_r[((size_t)(h * 16 + t)) * 128 + d] = res;
    } else {
      int g = (b - 512) >> 4;
      out_k[((size_t)(g * 16 + t)) * 128 + d] = res;
    }
  } else {
    int bb = b - 640;
#pragma unroll
    for (int i = 0; i < 16; i++) {
      int idx = bb * 2048 + i * 128 + d;  // [g][t][d]
      int g = idx >> 11; int t2 = (idx >> 7) & 15; int dd = idx & 127;
      size_t sidx = (size_t)t2 * KVDIM + g * HEAD_DIM + dd;
      out_v[idx] = v_ws[sidx] + v_ws[16384 + sidx];
    }
  }
}

// ---------------- scores = q @ K^T * scale + mask (LDS-staged K) ----------------
// grid = 8 g * 64 jb (64 j each) = 512 blocks, 256 threads.
__global__ __launch_bounds__(256) void scores_kernel(const float* __restrict__ q_r,
                                                     const float* __restrict__ ck,
                                                     const float* __restrict__ nk,
                                                     float* __restrict__ sc) {
  int g = blockIdx.x >> 6;
  int jb = blockIdx.x & 63;
  int jbase = jb * 64;
  int tid = threadIdx.x;
  __shared__ float sK[64][132];
  // stage K tile: 64 rows x 128 floats, coalesced b128
#pragma unroll
  for (int i = 0; i < 8; i++) {
    int f4 = i * 256 + tid;          // 2048 float4s
    int jr = f4 >> 5, c4 = f4 & 31;
    int j = jbase + jr;
    const float* kp = (j < TCACHE) ? ck + ((size_t)g * TCACHE + j) * 128
                                   : nk + ((size_t)g * 16 + (j - TCACHE)) * 128;
    *(float4*)&sK[jr][c4 * 4] = ld4(kp + c4 * 4);
  }
  __syncthreads();
  int jq = tid & 15;        // j = jbase + jq + 16*jj
  int qs = tid >> 4;        // qrows qs*4 .. qs*4+3
  float acc[4][4];
#pragma unroll
  for (int qq = 0; qq < 4; qq++)
#pragma unroll
    for (int jj = 0; jj < 4; jj++) acc[qq][jj] = 0.f;
  const float* qb = q_r + ((size_t)g * 64 + qs * 4) * 128;
  for (int d0 = 0; d0 < 128; d0 += 4) {
    float4 q4[4];
#pragma unroll
    for (int qq = 0; qq < 4; qq++) q4[qq] = ld4(qb + qq * 128 + d0);
    float4 k4[4];
#pragma unroll
    for (int jj = 0; jj < 4; jj++) k4[jj] = *(const float4*)&sK[jq + 16 * jj][d0];
#pragma unroll
    for (int qq = 0; qq < 4; qq++)
#pragma unroll
      for (int jj = 0; jj < 4; jj++)
        acc[qq][jj] += q4[qq].x * k4[jj].x + q4[qq].y * k4[jj].y +
                       q4[qq].z * k4[jj].z + q4[qq].w * k4[jj].w;
  }
  const float scale = 0.08838834764831845f;
#pragma unroll
  for (int qq = 0; qq < 4; qq++) {
    int qrow = qs * 4 + qq;
    int t = qrow & 15;
#pragma unroll
    for (int jj = 0; jj < 4; jj++) {
      int j = jbase + jq + 16 * jj;
      float m = (j >= TCACHE && (j - TCACHE) > t) ? -1e9f : 0.f;
      sc[((size_t)g * 64 + qrow) * TTOT + j] = acc[qq][jj] * scale + m;
    }
  }
}

// ---------------- softmax over 4096, one block per (h,t) row ----------------
__global__ void softmax_kernel(float* __restrict__ sc) {
  int row = blockIdx.x;
  int tid = threadIdx.x;
  float* p = sc + (size_t)row * TTOT;
  float4 v[4];
  float mx = -1e30f;
#pragma unroll
  for (int i = 0; i < 4; i++) {
    v[i] = ld4(p + (i * 256 + tid) * 4);
    mx = fmaxf(mx, fmaxf(fmaxf(v[i].x, v[i].y), fmaxf(v[i].z, v[i].w)));
  }
#pragma unroll
  for (int off = 32; off > 0; off >>= 1) mx = fmaxf(mx, __shfl_down(mx, off, 64));
  __shared__ float rmax[4], rsum[4];
  if ((tid & 63) == 0) rmax[tid >> 6] = mx;
  __syncthreads();
  mx = fmaxf(fmaxf(rmax[0], rmax[1]), fmaxf(rmax[2], rmax[3]));
  float sum = 0.f;
#pragma unroll
  for (int i = 0; i < 4; i++) {
    v[i].x = __expf(v[i].x - mx); v[i].y = __expf(v[i].y - mx);
    v[i].z = __expf(v[i].z - mx); v[i].w = __expf(v[i].w - mx);
    sum += v[i].x + v[i].y + v[i].z + v[i].w;
  }
#pragma unroll
  for (int off = 32; off > 0; off >>= 1) sum += __shfl_down(sum, off, 64);
  if ((tid & 63) == 0) rsum[tid >> 6] = sum;
  __syncthreads();
  sum = rsum[0] + rsum[1] + rsum[2] + rsum[3];
  float inv = 1.f / sum;
#pragma unroll
  for (int i = 0; i < 4; i++) {
    float4 o = v[i];
    o.x *= inv; o.y *= inv; o.z *= inv; o.w *= inv;
    *(float4*)(p + (i * 256 + tid) * 4) = o;
  }
}

// ---------------- attn @ V (LDS-staged attn, coalesced V) ----------------
// grid: g(8) x jc(8: 512 j) x dh(4: 32 d) = 256 blocks, 256 threads.
// thread: dq = tid&7 (d = dh*32 + dq*4), qs = tid>>3 (qrows qs*2, qs*2+1)
__global__ __launch_bounds__(256) void pv_kernel(const float* __restrict__ attn,
                                                 const float* __restrict__ cv,
                                                 const float* __restrict__ nv,
                                                 float* __restrict__ part) {
  int bx = blockIdx.x;
  int g = bx >> 5;
  int jc = (bx >> 2) & 7;
  int dh = bx & 3;
  int tid = threadIdx.x;
  int dq = tid & 7;
  int qs = tid >> 3;
  int d = dh * 32 + dq * 4;
  __shared__ float sA[64][260];
  float4 acc[2] = {make_float4(0.f,0.f,0.f,0.f), make_float4(0.f,0.f,0.f,0.f)};
  for (int th = 0; th < 2; th++) {
    int jtile = jc * 512 + th * 256;
    if (th) __syncthreads();
    // stage attn[64][256] tile
#pragma unroll
    for (int i = 0; i < 16; i++) {
      int f4 = i * 256 + tid;       // 4096 float4s
      int row = f4 >> 6, c4 = f4 & 63;
      *(float4*)&sA[row][c4 * 4] = ld4(attn + ((size_t)g * 64 + row) * TTOT + jtile + c4 * 4);
    }
    __syncthreads();
    for (int j0 = 0; j0 < 256; j0 += 4) {
      float4 a4[2];
#pragma unroll
      for (int qq = 0; qq < 2; qq++) a4[qq] = *(const float4*)&sA[qs * 2 + qq][j0];
#pragma unroll
      for (int jj = 0; jj < 4; jj++) {
        int j = jtile + j0 + jj;
        const float* vp = (j < TCACHE) ? cv + ((size_t)g * TCACHE + j) * 128 + d
                                       : nv + ((size_t)g * 16 + (j - TCACHE)) * 128 + d;
        float4 v4 = ld4(vp);
#pragma unroll
        for (int qq = 0; qq < 2; qq++) {
          float a = ((const float*)&a4[qq])[jj];
          acc[qq].x += a * v4.x; acc[qq].y += a * v4.y;
          acc[qq].z += a * v4.z; acc[qq].w += a * v4.w;
        }
      }
    }
  }
#pragma unroll
  for (int qq = 0; qq < 2; qq++) {
    int qrow = qs * 2 + qq;
    *(float4*)&part[(size_t)jc * 65536 + ((size_t)g * 64 + qrow) * 128 + d] = acc[qq];
  }
}

// ---------------- reduce pv partials (8) + flatten to [t][h*128+d] ----------------
__global__ void pv_reduce_kernel(const float* __restrict__ pp, float* __restrict__ aflat) {
  int idx = blockIdx.x * 256 + threadIdx.x;  // 0..65535, = (h*16+t)*128 + d
  float s = 0.f;
#pragma unroll
  for (int p = 0; p < 8; p++) s += pp[(size_t)p * 65536 + idx];
  int hh = idx >> 11;
  int t = (idx >> 7) & 15;
  int dd = idx & 127;
  aflat[(size_t)t * QDIM + hh * 128 + dd] = s;
}

// ---------------- h = x + sum of 4 o-partials ; y2 = rmsnorm(h) ----------------
__global__ void resid_rms_kernel(const float* __restrict__ x, const float* __restrict__ p,
                                 const float* __restrict__ w, float* __restrict__ h,
                                 float* __restrict__ y2) {
  int t = blockIdx.x;
  int tid = threadIdx.x;
  float v[10];
  float ss = 0.f;
#pragma unroll
  for (int i = 0; i < 10; i++) {
    int idx = i * 256 + tid;
    size_t gidx = (size_t)t * HIDDEN + idx;
    float hv = x[gidx] + p[gidx] + p[40960 + gidx] + p[81920 + gidx] + p[122880 + gidx];
    h[gidx] = hv;
    v[i] = hv;
    ss += hv * hv;
  }
#pragma unroll
  for (int off = 32; off > 0; off >>= 1) ss += __shfl_down(ss, off, 64);
  __shared__ float sred[4];
  if ((tid & 63) == 0) sred[tid >> 6] = ss;
  __syncthreads();
  ss = sred[0] + sred[1] + sred[2] + sred[3];
  float r = rsqrtf(ss / (float)HIDDEN + 1e-6f);
#pragma unroll
  for (int i = 0; i < 10; i++) {
    int idx = i * 256 + tid;
    y2[(size_t)t * HIDDEN + idx] = v[i] * r * w[idx];
  }
}

// ---------------- out0 = h + sum(down partials) ----------------
__global__ void final_kernel(const float* __restrict__ h, const float* __restrict__ dp,
                             float* __restrict__ out) {
  int idx = blockIdx.x * 256 + threadIdx.x;  // 40960
  out[idx] = h[idx] + dp[idx] + dp[40960 + idx] + dp[81920 + idx] + dp[122880 + idx];
}

extern "C" void kernel_launch(void* const* d_in, const int* in_sizes, int n_in,
                              void* d_out, int out_size, void* d_ws, size_t ws_size,
                              hipStream_t stream) {
  const float* x       = (const float*)d_in[0];
  const float* cos_q   = (const float*)d_in[1];
  const float* sin_q   = (const float*)d_in[2];
  const float* cos_k   = (const float*)d_in[3];
  const float* sin_k   = (const float*)d_in[4];
  const float* cache_k = (const float*)d_in[5];
  const float* cache_v = (const float*)d_in[6];
  const float* iln     = (const float*)d_in[8];
  const float* pln     = (const float*)d_in[9];
  const float* qnw     = (const float*)d_in[10];
  const float* knw     = (const float*)d_in[11];
  const float* qw      = (const float*)d_in[12];
  const float* kw      = (const float*)d_in[13];
  const float* vw      = (const float*)d_in[14];
  const float* ow      = (const float*)d_in[15];
  const float* gw      = (const float*)d_in[16];
  const float* uw      = (const float*)d_in[17];
  const float* dw      = (const float*)d_in[18];

  float* out0 = (float*)d_out;
  float* outk = out0 + 40960;
  float* outv = out0 + 57344;

  float* ws    = (float*)d_ws;
  float* y     = ws;                  // 40960
  float* q_ws  = y + 40960;           // 2*65536
  float* k_ws  = q_ws + 131072;       // 2*16384
  float* v_ws  = k_ws + 32768;        // 2*16384
  float* q_r   = v_ws + 32768;        // 65536
  float* sc    = q_r + 65536;         // 2097152
  float* pvp   = sc + 2097152;        // 8*65536
  float* aflat = pvp + 524288;        // 65536
  float* opart = aflat + 65536;       // 4*40960
  float* h     = opart + 163840;      // 40960
  float* y2    = h + 40960;           // 40960
  // overlap with sc (dead after pv_kernel):
  float* g_tmp = sc;                  // 155648
  float* u_tmp = sc + 155648;         // 155648
  float* act   = sc + 311296;         // 155648
  float* dpart = sc + 466944;         // 4*40960

  rms_kernel<<<16, 256, 0, stream>>>(x, iln, y);
  gemv16_kernel<<<512, 256, 0, stream>>>(y, qw, q_ws, QDIM, HIDDEN, 1280, 256);
  gemv16_kernel<<<128, 256, 0, stream>>>(y, kw, k_ws, KVDIM, HIDDEN, 1280, 64);
  gemv16_kernel<<<128, 256, 0, stream>>>(y, vw, v_ws, KVDIM, HIDDEN, 1280, 64);
  normrope_kernel<<<648, 128, 0, stream>>>(q_ws, k_ws, v_ws, qnw, knw, cos_q, sin_q,
                                           cos_k, sin_k, q_r, outk, outv);
  scores_kernel<<<512, 256, 0, stream>>>(q_r, cache_k, outk, sc);
  softmax_kernel<<<512, 256, 0, stream>>>(sc);
  pv_kernel<<<256, 256, 0, stream>>>(sc, cache_v, outv, pvp);
  pv_reduce_kernel<<<256, 256, 0, stream>>>(pvp, aflat);
  gemv16_kernel<<<640, 256, 0, stream>>>(aflat, ow, opart, HIDDEN, QDIM, 1024, 160);
  resid_rms_kernel<<<16, 256, 0, stream>>>(x, opart, pln, h, y2);
  gateup16_kernel<<<1216, 256, 0, stream>>>(y2, gw, uw, g_tmp, u_tmp);
  silu_kernel<<<608, 256, 0, stream>>>(g_tmp, u_tmp, act);
  gemv16_kernel<<<640, 256, 0, stream>>>(act, dw, dpart, HIDDEN, INTER, 2560, 160);
  final_kernel<<<160, 256, 0, stream>>>(h, dpart, out0);
}